// Round 19
// baseline (98.501 us; speedup 1.0000x reference)
//
#include <hip/hip_runtime.h>
#include <hip/hip_bf16.h>

#define T_LEN 1024
#define BATCH 128
#define NM 131072   // T_LEN*BATCH

typedef __attribute__((ext_vector_type(8))) short short8;
typedef __attribute__((ext_vector_type(4))) float f32x4;

__device__ __forceinline__ float b2f(ushort u) {
  union { uint i; float f; } c; c.i = ((uint)u) << 16; return c.f;
}
__device__ __forceinline__ ushort f2b(float f) {
  __hip_bfloat16 h = __float2bfloat16(f);
  return *reinterpret_cast<ushort*>(&h);
}
__device__ __forceinline__ uint pack2(float a, float b) {
  return (uint)f2b(a) | ((uint)f2b(b) << 16);
}

// ---- k_pre: streaming m-order pass: argmax -> idx[m], fp32->bf16 -> Xm[m][80] ----
__global__ __launch_bounds__(256) void k_pre(const float* __restrict__ inp,
                                             ushort* __restrict__ Xm, int* __restrict__ idx) {
  int tid = threadIdx.x;
  int m = blockIdx.x * 64 + (tid >> 2);
  int q = tid & 3;
  const float* rp = inp + (size_t)m * 80 + q * 20;
  float v[20];
  #pragma unroll
  for (int i = 0; i < 5; ++i) {
    float4 u4 = *(const float4*)(rp + i*4);
    v[i*4+0]=u4.x; v[i*4+1]=u4.y; v[i*4+2]=u4.z; v[i*4+3]=u4.w;
  }
  float best = v[0]; int bi = q*20;
  #pragma unroll
  for (int i = 1; i < 20; ++i) if (v[i] > best) { best = v[i]; bi = q*20 + i; }
  #pragma unroll
  for (int d = 1; d <= 2; d <<= 1) {
    float ob = __shfl_xor(best, d);
    int   oi = __shfl_xor(bi, d);
    if (ob > best || (ob == best && oi < bi)) { best = ob; bi = oi; }
  }
  if (q == 0) idx[m] = bi;
  ushort* orow = Xm + (size_t)m * 80 + q * 20;
  #pragma unroll
  for (int i = 0; i < 5; ++i) {
    uint2 pk; pk.x = pack2(v[i*4], v[i*4+1]); pk.y = pack2(v[i*4+2], v[i*4+3]);
    *(uint2*)(orow + i*4) = pk;
  }
}

// ---- k_prep: fused [gconst | prepw] by block range ----
__global__ __launch_bounds__(256) void k_prep(const float* __restrict__ gsty,
    const float* __restrict__ w1, const float* __restrict__ b1,
    const float* __restrict__ w2, const float* __restrict__ w3,
    float* __restrict__ Gfull, float* __restrict__ Gk0, float* __restrict__ Gk2,
    ushort* __restrict__ Wp1, ushort* __restrict__ Wp2, ushort* __restrict__ Wp3) {
  int bid = blockIdx.x, tid = threadIdx.x;
  if (bid < 128) {
    // ---- gconst ----
    int b = bid;
    __shared__ float gl[256];
    gl[tid] = gsty[b*256 + tid];
    __syncthreads();
    if (tid < 128) {
      int o = tid;
      const float* wr = w1 + (size_t)o*1200 + 240;   // channels 80..335
      float s0 = 0.f, s1 = 0.f, s2 = 0.f;
      for (int c = 0; c < 256; ++c) {
        float g = gl[c];
        s0 += wr[c*3+0]*g; s1 += wr[c*3+1]*g; s2 += wr[c*3+2]*g;
      }
      Gk0[b*128+o] = s0;
      Gk2[b*128+o] = s2;
      Gfull[b*128+o] = s0 + s1 + s2 + b1[o];
    }
  } else {
    // ---- prepw: bf16 pack, cols 0..79 inp ch, 80..95 zero, 96..159 char ch ----
    int e = (bid - 128)*256 + tid;
    if (e < 61440) {
      int o = e / 480, r = e % 480, k = r / 160, c = r % 160;
      float v = 0.f;
      if (c < 80)       v = w1[(size_t)o*1200 + c*3 + k];
      else if (c >= 96) v = w1[(size_t)o*1200 + (336 + (c-96))*3 + k];
      Wp1[e] = f2b(v);
    } else if (e < 61440 + 24576) {
      int e2 = e - 61440;
      int o = e2/384, r = e2%384, k = r/128, c = r%128;
      Wp2[e2] = f2b(w2[(size_t)o*384 + c*3 + k]);
    } else if (e < 61440 + 24576 + 6144) {
      int e3 = e - 61440 - 24576;
      int o = e3/192, r = e3%192, k = r/64, c = r%64;
      Wp3[e3] = f2b(w3[(size_t)o*192 + c*3 + k]);
    }
  }
}

// ---- conv1 staging helpers ----
__device__ __forceinline__ uint4 c1_ldx16(const ushort* __restrict__ Xm, int b, int cc, int t0, int task) {
  int r = task >> 2, q = task & 3;
  int t = t0 - 1 + r;
  int c8 = cc*32 + q*8;
  if (t >= 0 && t < T_LEN && c8 < 80)
    return *(const uint4*)(Xm + ((size_t)t*BATCH + b)*80 + c8);
  return make_uint4(0u,0u,0u,0u);
}
__device__ __forceinline__ uint4 packf(float4 a, float4 b) {
  uint4 p;
  p.x = pack2(a.x, a.y); p.y = pack2(a.z, a.w);
  p.z = pack2(b.x, b.y); p.w = pack2(b.z, b.w);
  return p;
}
__device__ __forceinline__ uint4 c1_ldcs(const float* __restrict__ cs, const int* idxs,
                                         int b, int cc, int t0, int task) {
  int r = task >> 2, q = task & 3;
  int t = t0 - 1 + r;
  if (t >= 0 && t < T_LEN) {
    int jc = idxs[r];
    const float* src = cs + ((size_t)b*80 + jc)*64 + (cc-3)*32 + q*8;
    float4 fa = *(const float4*)src;
    float4 fb = *(const float4*)(src + 4);
    return packf(fa, fb);
  }
  return make_uint4(0u,0u,0u,0u);
}
__device__ __forceinline__ short8 c1_ldw(const ushort* Wp1, int cc, int task) {
  int o = task / 12, seg = task % 12;
  int k = seg >> 2, oct = seg & 3;
  return *(const short8*)(Wp1 + (size_t)o*480 + k*160 + cc*32 + oct*8);
}
__device__ __forceinline__ void c1_wrx(ushort (*Xsb)[40], int task, uint4 v) {
  int r = task >> 2, q = task & 3;
  *(uint4*)&Xsb[r][q*8] = v;
}
__device__ __forceinline__ void c1_wrw(ushort (*Wsb)[104], int task, short8 v) {
  int o = task / 12, seg = task % 12;
  *(short8*)&Wsb[o][seg*8] = v;
}

// ---- conv1: 2-phase pipelined GEMM, full N=128; chunks 0-2 from bf16 Xm, 3-4 from cs ----
__global__ __launch_bounds__(256) void k_conv1(const ushort* __restrict__ Xm, const float* __restrict__ cs,
    const int* __restrict__ idx, const ushort* __restrict__ Wp1,
    const float* __restrict__ Gfull, const float* __restrict__ Gk0, const float* __restrict__ Gk2,
    ushort* __restrict__ y1, float2* __restrict__ part1) {
  __shared__ __align__(16) ushort Xs[2][130][40];
  __shared__ __align__(16) ushort Ws[2][128][104];
  __shared__ float gf[128], g0v[128], g2v[128];
  __shared__ float ps[4][128], pq[4][128];
  __shared__ int idxs[130];
  int b = blockIdx.x, tt = blockIdx.y;
  int t0 = tt * 128;
  int tid = threadIdx.x, lane = tid & 63, wave = tid >> 6;
  int ln = lane & 15, lq = lane >> 4, wt = wave * 32;

  if (tid < 130) {
    int t = t0 - 1 + tid;
    idxs[tid] = (t >= 0 && t < T_LEN) ? idx[t*BATCH + b] : 0;
  }
  if (tid < 128) {
    gf[tid]  = Gfull[b*128 + tid];
    g0v[tid] = Gk0[b*128 + tid];
    g2v[tid] = Gk2[b*128 + tid];
  }
  f32x4 acc[2][8];
  #pragma unroll
  for (int m = 0; m < 2; ++m)
    #pragma unroll
    for (int n = 0; n < 8; ++n) { f32x4 z = {0.f,0.f,0.f,0.f}; acc[m][n] = z; }

  uint4 rx0, rx1, rx2;
  short8 rw[6];

  // prologue: chunk 0 (bf16 Xm path)
  rx0 = c1_ldx16(Xm, b, 0, t0, tid);
  rx1 = c1_ldx16(Xm, b, 0, t0, tid + 256);
  if (tid < 8) rx2 = c1_ldx16(Xm, b, 0, t0, tid + 512);
  #pragma unroll
  for (int i = 0; i < 6; ++i) rw[i] = c1_ldw(Wp1, 0, tid + i*256);
  c1_wrx(Xs[0], tid, rx0);
  c1_wrx(Xs[0], tid + 256, rx1);
  if (tid < 8) c1_wrx(Xs[0], tid + 512, rx2);
  #pragma unroll
  for (int i = 0; i < 6; ++i) c1_wrw(Ws[0], tid + i*256, rw[i]);
  __syncthreads();

  for (int cc = 0; cc < 5; ++cc) {
    bool more = (cc < 4);
    if (more) {
      if (cc + 1 < 3) {
        rx0 = c1_ldx16(Xm, b, cc+1, t0, tid);
        rx1 = c1_ldx16(Xm, b, cc+1, t0, tid + 256);
        if (tid < 8) rx2 = c1_ldx16(Xm, b, cc+1, t0, tid + 512);
      } else {
        rx0 = c1_ldcs(cs, idxs, b, cc+1, t0, tid);
        rx1 = c1_ldcs(cs, idxs, b, cc+1, t0, tid + 256);
        if (tid < 8) rx2 = c1_ldcs(cs, idxs, b, cc+1, t0, tid + 512);
      }
      #pragma unroll
      for (int i = 0; i < 6; ++i) rw[i] = c1_ldw(Wp1, cc+1, tid + i*256);
    }
    int cur = cc & 1;
    #pragma unroll
    for (int k = 0; k < 3; ++k) {
      short8 a0 = *(const short8*)&Xs[cur][wt + ln + k][lq*8];
      short8 a1 = *(const short8*)&Xs[cur][wt + 16 + ln + k][lq*8];
      #pragma unroll
      for (int nt = 0; nt < 8; ++nt) {
        short8 bb = *(const short8*)&Ws[cur][nt*16 + ln][k*32 + lq*8];
        acc[0][nt] = __builtin_amdgcn_mfma_f32_16x16x32_bf16(a0, bb, acc[0][nt], 0, 0, 0);
        acc[1][nt] = __builtin_amdgcn_mfma_f32_16x16x32_bf16(a1, bb, acc[1][nt], 0, 0, 0);
      }
    }
    if (more) {
      int nxt = cur ^ 1;
      c1_wrx(Xs[nxt], tid, rx0);
      c1_wrx(Xs[nxt], tid + 256, rx1);
      if (tid < 8) c1_wrx(Xs[nxt], tid + 512, rx2);
      #pragma unroll
      for (int i = 0; i < 6; ++i) c1_wrw(Ws[nxt], tid + i*256, rw[i]);
    }
    __syncthreads();
  }

  // epilogue: gconst (+edge), bf16 store to y1[b][o][t], fused partial stats
  #pragma unroll
  for (int nt = 0; nt < 8; ++nt) {
    int o = nt*16 + ln;
    float add = gf[o];
    float s = 0.f, sq = 0.f;
    #pragma unroll
    for (int mt = 0; mt < 2; ++mt) {
      int tb = t0 + wt + mt*16 + lq*4;
      float vv[4];
      #pragma unroll
      for (int r = 0; r < 4; ++r) {
        float v = acc[mt][nt][r] + add;
        int t = tb + r;
        if (t == 0) v -= g0v[o];
        if (t == T_LEN-1) v -= g2v[o];
        vv[r] = v; s += v; sq += v*v;
      }
      uint2 pk;
      pk.x = pack2(vv[0], vv[1]);
      pk.y = pack2(vv[2], vv[3]);
      *(uint2*)(y1 + ((size_t)b*128 + o)*T_LEN + tb) = pk;
    }
    s  += __shfl_xor(s, 16);  s  += __shfl_xor(s, 32);
    sq += __shfl_xor(sq, 16); sq += __shfl_xor(sq, 32);
    if (lane < 16) { ps[wave][o] = s; pq[wave][o] = sq; }
  }
  __syncthreads();
  if (tid < 128) {
    float S = ps[0][tid]+ps[1][tid]+ps[2][tid]+ps[3][tid];
    float Q = pq[0][tid]+pq[1][tid]+pq[2][tid]+pq[3][tid];
    part1[((size_t)b*128 + tid)*8 + tt] = make_float2(S, Q);
  }
}

// ---- convmid W staging helpers ----
__device__ __forceinline__ short8 mid_ldw(const ushort* Wp, int cin, int cc, int task) {
  int o = task / 12, seg = task % 12;
  int k = seg >> 2, oct = seg & 3;
  return *(const short8*)(Wp + ((size_t)o*3 + k)*cin + cc*32 + oct*8);
}
__device__ __forceinline__ void mid_wrw(ushort (*Wsb)[104], int task, short8 v) {
  int o = task / 12, seg = task % 12;
  *(short8*)&Wsb[o][seg*8] = v;
}

// ---- mid convs: fused GN-stats prologue, 2-phase pipeline, fused out-stats ----
template<int NC, int CO, int NT, int CPG>
__global__ __launch_bounds__(256) void k_convmid(const ushort* __restrict__ xin,
    const ushort* __restrict__ Wp, const float* __restrict__ bias,
    const float2* __restrict__ partin, const float* __restrict__ gs, const float* __restrict__ gb,
    ushort* __restrict__ yout, float2* __restrict__ part) {
  constexpr int CIN = NC*32;
  constexpr int NG = CIN/CPG;
  __shared__ __align__(16) ushort Xs[2][130][40];
  __shared__ __align__(16) ushort Ws[2][CO][104];
  __shared__ float2 affl[CIN];
  __shared__ float ssb[CIN], qqb[CIN];
  __shared__ float2 gmr[NG];
  __shared__ float bl[CO];
  __shared__ float ps[4][CO], pq[4][CO];
  int b = blockIdx.x, tt = blockIdx.y, t0 = tt*128;
  int tid = threadIdx.x, lane = tid & 63, wave = tid >> 6;
  int ln = lane & 15, lq = lane >> 4, wt = wave*32;
  int cp = (tid & 15)*2, j = tid >> 4;
  int er = (tid < 32) ? 0 : 129, eci = tid & 31;
  const ushort* xb = xin + (size_t)b * CIN * T_LEN;

  if (tid < CIN) {
    const float2* p = partin + (size_t)(b*CIN + tid)*8;
    float S = 0.f, Q = 0.f;
    #pragma unroll
    for (int j2 = 0; j2 < 8; ++j2) { float2 v = p[j2]; S += v.x; Q += v.y; }
    ssb[tid] = S; qqb[tid] = Q;
  }
  if (tid < CO)  bl[tid]  = bias[tid];

  f32x4 acc[2][NT];
  #pragma unroll
  for (int m = 0; m < 2; ++m)
    #pragma unroll
    for (int n = 0; n < NT; ++n) { f32x4 z = {0.f,0.f,0.f,0.f}; acc[m][n] = z; }

  short8 v0, v1;
  ushort ev = 0;
  short8 rw0, rw1, rw2;
  int te = t0 - 1 + er;

  {
    const ushort* s0 = xb + (size_t)cp * T_LEN + t0 + j*8;
    v0 = *(const short8*)s0;
    v1 = *(const short8*)(s0 + T_LEN);
    ev = 0;
    if (tid < 64 && te >= 0 && te < T_LEN) ev = xb[(size_t)eci * T_LEN + te];
    rw0 = mid_ldw(Wp, CIN, 0, tid);
    if constexpr (CO == 64) {
      rw1 = mid_ldw(Wp, CIN, 0, tid + 256);
      rw2 = mid_ldw(Wp, CIN, 0, tid + 512);
    } else {
      if (tid < 128) rw1 = mid_ldw(Wp, CIN, 0, tid + 256);
    }
  }
  __syncthreads();   // ssb/qqb ready
  if (tid < NG) {
    float S = 0.f, Q = 0.f;
    #pragma unroll
    for (int ci = 0; ci < CPG; ++ci) { S += ssb[tid*CPG+ci]; Q += qqb[tid*CPG+ci]; }
    float invn = 1.f / (float)(CPG * T_LEN);
    float m = S * invn;
    float var = Q * invn - m*m;
    gmr[tid] = make_float2(m, rsqrtf(var + 1e-5f));
  }
  __syncthreads();   // gmr ready
  if (tid < CIN) {
    float2 mr = gmr[tid / CPG];
    float a = mr.y * gs[tid];
    affl[tid] = make_float2(a, gb[tid] - mr.x * a);
  }
  __syncthreads();   // affl ready
  {
    float2 A0 = affl[cp], A1 = affl[cp+1];
    #pragma unroll
    for (int e = 0; e < 8; ++e) {
      float f0 = fmaxf(0.f, b2f((ushort)v0[e])*A0.x + A0.y);
      float f1 = fmaxf(0.f, b2f((ushort)v1[e])*A1.x + A1.y);
      *(uint*)&Xs[0][1 + j*8 + e][cp] = pack2(f0, f1);
    }
    if (tid < 64) {
      ushort val = 0;
      if (te >= 0 && te < T_LEN) { float2 A = affl[eci]; val = f2b(fmaxf(0.f, b2f(ev)*A.x + A.y)); }
      Xs[0][er][eci] = val;
    }
    mid_wrw(Ws[0], tid, rw0);
    if constexpr (CO == 64) {
      mid_wrw(Ws[0], tid + 256, rw1);
      mid_wrw(Ws[0], tid + 512, rw2);
    } else {
      if (tid < 128) mid_wrw(Ws[0], tid + 256, rw1);
    }
  }
  __syncthreads();

  for (int cc = 0; cc < NC; ++cc) {
    bool more = (cc + 1 < NC);
    if (more) {
      const ushort* s0 = xb + (size_t)((cc+1)*32 + cp) * T_LEN + t0 + j*8;
      v0 = *(const short8*)s0;
      v1 = *(const short8*)(s0 + T_LEN);
      ev = 0;
      if (tid < 64 && te >= 0 && te < T_LEN) ev = xb[(size_t)((cc+1)*32 + eci) * T_LEN + te];
      rw0 = mid_ldw(Wp, CIN, cc+1, tid);
      if constexpr (CO == 64) {
        rw1 = mid_ldw(Wp, CIN, cc+1, tid + 256);
        rw2 = mid_ldw(Wp, CIN, cc+1, tid + 512);
      } else {
        if (tid < 128) rw1 = mid_ldw(Wp, CIN, cc+1, tid + 256);
      }
    }
    int cur = cc & 1;
    #pragma unroll
    for (int k = 0; k < 3; ++k) {
      short8 a0 = *(const short8*)&Xs[cur][wt + ln + k][lq*8];
      short8 a1 = *(const short8*)&Xs[cur][wt + 16 + ln + k][lq*8];
      #pragma unroll
      for (int nt = 0; nt < NT; ++nt) {
        short8 bb = *(const short8*)&Ws[cur][nt*16 + ln][k*32 + lq*8];
        acc[0][nt] = __builtin_amdgcn_mfma_f32_16x16x32_bf16(a0, bb, acc[0][nt], 0, 0, 0);
        acc[1][nt] = __builtin_amdgcn_mfma_f32_16x16x32_bf16(a1, bb, acc[1][nt], 0, 0, 0);
      }
    }
    if (more) {
      int nxt = cur ^ 1;
      float2 A0 = affl[(cc+1)*32 + cp], A1 = affl[(cc+1)*32 + cp + 1];
      #pragma unroll
      for (int e = 0; e < 8; ++e) {
        float f0 = fmaxf(0.f, b2f((ushort)v0[e])*A0.x + A0.y);
        float f1 = fmaxf(0.f, b2f((ushort)v1[e])*A1.x + A1.y);
        *(uint*)&Xs[nxt][1 + j*8 + e][cp] = pack2(f0, f1);
      }
      if (tid < 64) {
        ushort val = 0;
        if (te >= 0 && te < T_LEN) { float2 A = affl[(cc+1)*32 + eci]; val = f2b(fmaxf(0.f, b2f(ev)*A.x + A.y)); }
        Xs[nxt][er][eci] = val;
      }
      mid_wrw(Ws[nxt], tid, rw0);
      if constexpr (CO == 64) {
        mid_wrw(Ws[nxt], tid + 256, rw1);
        mid_wrw(Ws[nxt], tid + 512, rw2);
      } else {
        if (tid < 128) mid_wrw(Ws[nxt], tid + 256, rw1);
      }
    }
    __syncthreads();
  }

  #pragma unroll
  for (int nt = 0; nt < NT; ++nt) {
    int o = nt*16 + ln;
    float add = bl[o];
    float s = 0.f, sq = 0.f;
    #pragma unroll
    for (int mt = 0; mt < 2; ++mt) {
      int tb = t0 + wt + mt*16 + lq*4;
      float vv[4];
      #pragma unroll
      for (int r = 0; r < 4; ++r) {
        float v = acc[mt][nt][r] + add;
        vv[r] = v; s += v; sq += v*v;
      }
      uint2 pk;
      pk.x = pack2(vv[0], vv[1]);
      pk.y = pack2(vv[2], vv[3]);
      *(uint2*)(yout + ((size_t)b*CO + o)*T_LEN + tb) = pk;
    }
    s  += __shfl_xor(s, 16);  s  += __shfl_xor(s, 32);
    sq += __shfl_xor(sq, 16); sq += __shfl_xor(sq, 32);
    if (lane < 16) { ps[wave][o] = s; pq[wave][o] = sq; }
  }
  __syncthreads();
  if (tid < CO) {
    float S = ps[0][tid]+ps[1][tid]+ps[2][tid]+ps[3][tid];
    float Q = pq[0][tid]+pq[1][tid]+pq[2][tid]+pq[3][tid];
    part[((size_t)b*CO + tid)*8 + tt] = make_float2(S, Q);
  }
}

// ---- final: fused GN3-stats prologue + gn3+relu + 1x1 conv + affine + transpose ----
__global__ __launch_bounds__(256) void k_final(const ushort* __restrict__ y3, const float2* __restrict__ part3,
    const float* __restrict__ s3, const float* __restrict__ b3,
    const float* __restrict__ w4, const float* __restrict__ b4,
    const float* __restrict__ mn, const float* __restrict__ sd, float* __restrict__ out) {
  int b = blockIdx.x;
  int t = blockIdx.y * 256 + threadIdx.x;
  __shared__ float wl[32];
  __shared__ float2 al[32];
  if (threadIdx.x < 32) {
    int c = threadIdx.x;
    const float2* p = part3 + (size_t)(b*32 + c)*8;
    float S = 0.f, Q = 0.f;
    #pragma unroll
    for (int j = 0; j < 8; ++j) { float2 v = p[j]; S += v.x; Q += v.y; }
    float invn = 1.f / (float)T_LEN;
    float m = S * invn;
    float var = Q * invn - m*m;
    float rs = rsqrtf(var + 1e-5f);
    float a = rs * s3[c];
    al[c] = make_float2(a, b3[c] - m*a);
    wl[c] = w4[c];
  }
  __syncthreads();
  float s = b4[0];
  #pragma unroll 8
  for (int c = 0; c < 32; ++c) {
    float v = b2f(y3[((size_t)b*32 + c)*T_LEN + t]);
    float2 A = al[c];
    s += wl[c] * fmaxf(0.f, v*A.x + A.y);
  }
  out[(size_t)t*BATCH + b] = s*sd[0] + mn[0];
}

extern "C" void kernel_launch(void* const* d_in, const int* in_sizes, int n_in,
                              void* d_out, int out_size, void* d_ws, size_t ws_size,
                              hipStream_t stream) {
  const float* inp  = (const float*)d_in[0];
  const float* gsty = (const float*)d_in[1];
  const float* cs   = (const float*)d_in[3];
  const float* w1   = (const float*)d_in[4];
  const float* b1   = (const float*)d_in[5];
  const float* gn1s = (const float*)d_in[6];
  const float* gn1b = (const float*)d_in[7];
  const float* w2   = (const float*)d_in[8];
  const float* b2   = (const float*)d_in[9];
  const float* gn2s = (const float*)d_in[10];
  const float* gn2b = (const float*)d_in[11];
  const float* w3   = (const float*)d_in[12];
  const float* b3   = (const float*)d_in[13];
  const float* gn3s = (const float*)d_in[14];
  const float* gn3b = (const float*)d_in[15];
  const float* w4   = (const float*)d_in[16];
  const float* b4   = (const float*)d_in[17];
  const float* mn   = (const float*)d_in[18];
  const float* sd   = (const float*)d_in[19];
  float* out = (float*)d_out;
  ushort* wsu = (ushort*)d_ws;

  ushort* Xm  = wsu;                               // NM*80 = 10485760 sh
  int*    idx = (int*)(Xm + (size_t)10485760);     // NM ints = 262144 sh
  ushort* Wp1 = (ushort*)(idx + NM);               // 61440 sh
  ushort* Wp2 = Wp1 + 61440;                       // 24576 sh
  ushort* Wp3 = Wp2 + 24576;                       // 6144 sh
  float* Gfull = (float*)(Wp3 + 6144);             // 16384 f
  float* Gk0   = Gfull + 16384;
  float* Gk2   = Gk0 + 16384;
  ushort* y1 = (ushort*)(Gk2 + 16384);             // 128*128*1024 sh
  ushort* y2 = y1 + (size_t)NM*128;                // 128*64*1024
  ushort* y3 = y2 + (size_t)NM*64;                 // 128*32*1024
  float2* part1 = (float2*)(y3 + (size_t)NM*32);   // 128*128*8
  float2* part2 = part1 + 131072;                  // 128*64*8
  float2* part3 = part2 + 65536;                   // 128*32*8

  k_pre<<<2048, 256, 0, stream>>>(inp, Xm, idx);
  k_prep<<<488, 256, 0, stream>>>(gsty, w1, b1, w2, w3,
                                  Gfull, Gk0, Gk2, Wp1, Wp2, Wp3);
  k_conv1<<<dim3(128,8), 256, 0, stream>>>(Xm, cs, idx, Wp1, Gfull, Gk0, Gk2, y1, part1);
  k_convmid<4,64,4,4><<<dim3(128,8), 256, 0, stream>>>(y1, Wp2, b2, part1, gn1s, gn1b, y2, part2);
  k_convmid<2,32,2,2><<<dim3(128,8), 256, 0, stream>>>(y2, Wp3, b3, part2, gn2s, gn2b, y3, part3);
  k_final<<<dim3(128,4), 256, 0, stream>>>(y3, part3, gn3s, gn3b, w4, b4, mn, sd, out);
}

// Round 20
// 89.270 us; speedup vs baseline: 1.1034x; 1.1034x over previous
//
#include <hip/hip_runtime.h>
#include <hip/hip_bf16.h>

#define T_LEN 1024
#define BATCH 128
#define NM 131072   // T_LEN*BATCH

typedef __attribute__((ext_vector_type(8))) short short8;
typedef __attribute__((ext_vector_type(4))) float f32x4;

__device__ __forceinline__ float b2f(ushort u) {
  union { uint i; float f; } c; c.i = ((uint)u) << 16; return c.f;
}
__device__ __forceinline__ ushort f2b(float f) {
  __hip_bfloat16 h = __float2bfloat16(f);
  return *reinterpret_cast<ushort*>(&h);
}
__device__ __forceinline__ uint pack2(float a, float b) {
  return (uint)f2b(a) | ((uint)f2b(b) << 16);
}

// ---- k_prep: fused [gconst | prepw] by block range ----
__global__ __launch_bounds__(256) void k_prep(const float* __restrict__ gsty,
    const float* __restrict__ w1, const float* __restrict__ b1,
    const float* __restrict__ w2, const float* __restrict__ w3,
    float* __restrict__ Gfull, float* __restrict__ Gk0, float* __restrict__ Gk2,
    ushort* __restrict__ Wp1, ushort* __restrict__ Wp2, ushort* __restrict__ Wp3) {
  int bid = blockIdx.x, tid = threadIdx.x;
  if (bid < 128) {
    int b = bid;
    __shared__ float gl[256];
    gl[tid] = gsty[b*256 + tid];
    __syncthreads();
    if (tid < 128) {
      int o = tid;
      const float* wr = w1 + (size_t)o*1200 + 240;   // channels 80..335
      float s0 = 0.f, s1 = 0.f, s2 = 0.f;
      for (int c = 0; c < 256; ++c) {
        float g = gl[c];
        s0 += wr[c*3+0]*g; s1 += wr[c*3+1]*g; s2 += wr[c*3+2]*g;
      }
      Gk0[b*128+o] = s0;
      Gk2[b*128+o] = s2;
      Gfull[b*128+o] = s0 + s1 + s2 + b1[o];
    }
  } else {
    int e = (bid - 128)*256 + tid;
    if (e < 61440) {
      int o = e / 480, r = e % 480, k = r / 160, c = r % 160;
      float v = 0.f;
      if (c < 80)       v = w1[(size_t)o*1200 + c*3 + k];
      else if (c >= 96) v = w1[(size_t)o*1200 + (336 + (c-96))*3 + k];
      Wp1[e] = f2b(v);
    } else if (e < 61440 + 24576) {
      int e2 = e - 61440;
      int o = e2/384, r = e2%384, k = r/128, c = r%128;
      Wp2[e2] = f2b(w2[(size_t)o*384 + c*3 + k]);
    } else if (e < 61440 + 24576 + 6144) {
      int e3 = e - 61440 - 24576;
      int o = e3/192, r = e3%192, k = r/64, c = r%64;
      Wp3[e3] = f2b(w3[(size_t)o*192 + c*3 + k]);
    }
  }
}

// ---- conv1 staging helpers (R18: fused argmax, direct inp/cs) ----
__device__ __forceinline__ void c1_ldg(const float* __restrict__ inp, const float* __restrict__ cs,
                                       const int* idxs, int b, int cc, int t0, int task,
                                       float4& fa, float4& fb) {
  int r = task >> 2, q = task & 3;
  int t = t0 - 1 + r;
  fa = make_float4(0.f,0.f,0.f,0.f); fb = fa;
  if (t >= 0 && t < T_LEN) {
    const float* src;
    if (cc < 3) {
      int c8 = cc*32 + q*8;
      if (c8 >= 80) return;
      src = inp + ((size_t)t*BATCH + b)*80 + c8;
    } else {
      int jc = idxs[r];
      src = cs + ((size_t)b*80 + jc)*64 + (cc-3)*32 + q*8;
    }
    fa = *(const float4*)src;
    fb = *(const float4*)(src + 4);
  }
}
__device__ __forceinline__ void amax8(float& best, int& bi, float4 fa, float4 fb, int base, bool valid) {
  if (!valid) return;
  float v[8] = {fa.x, fa.y, fa.z, fa.w, fb.x, fb.y, fb.z, fb.w};
  #pragma unroll
  for (int i = 0; i < 8; ++i)
    if (v[i] > best) { best = v[i]; bi = base + i; }
}
__device__ __forceinline__ uint4 packf(float4 a, float4 b) {
  uint4 p;
  p.x = pack2(a.x, a.y); p.y = pack2(a.z, a.w);
  p.z = pack2(b.x, b.y); p.w = pack2(b.z, b.w);
  return p;
}
__device__ __forceinline__ short8 c1_ldw(const ushort* Wp1, int cc, int task) {
  int o = task / 12, seg = task % 12;
  int k = seg >> 2, oct = seg & 3;
  return *(const short8*)(Wp1 + (size_t)o*480 + k*160 + cc*32 + oct*8);
}
__device__ __forceinline__ void c1_wrx(ushort (*Xsb)[40], int task, uint4 v) {
  int r = task >> 2, q = task & 3;
  *(uint4*)&Xsb[r][q*8] = v;
}
__device__ __forceinline__ void c1_wrw(ushort (*Wsb)[104], int task, short8 v) {
  int o = task / 12, seg = task % 12;
  *(short8*)&Wsb[o][seg*8] = v;
}

// ---- conv1: R18 pipeline + fused argmax; NEW: LDS-transpose epilogue -> y1[b][t][128] ----
__global__ __launch_bounds__(256) void k_conv1(const float* __restrict__ inp, const float* __restrict__ cs,
    const ushort* __restrict__ Wp1,
    const float* __restrict__ Gfull, const float* __restrict__ Gk0, const float* __restrict__ Gk2,
    ushort* __restrict__ y1, float2* __restrict__ part1) {
  __shared__ __align__(16) ushort Xs[2][130][40];
  __shared__ __align__(16) ushort Ws[2][128][104];   // also aliased as transpose buffer Ts
  __shared__ float gf[128], g0v[128], g2v[128];
  __shared__ float ps[4][128], pq[4][128];
  __shared__ int idxs[130];
  int b = blockIdx.x, tt = blockIdx.y;
  int t0 = tt * 128;
  int tid = threadIdx.x, lane = tid & 63, wave = tid >> 6;
  int ln = lane & 15, lq = lane >> 4, wt = wave * 32;
  int q = tid & 3, u = tid >> 2;

  if (tid < 128) {
    gf[tid]  = Gfull[b*128 + tid];
    g0v[tid] = Gk0[b*128 + tid];
    g2v[tid] = Gk2[b*128 + tid];
  }
  f32x4 acc[2][8];
  #pragma unroll
  for (int m = 0; m < 2; ++m)
    #pragma unroll
    for (int n = 0; n < 8; ++n) { f32x4 z = {0.f,0.f,0.f,0.f}; acc[m][n] = z; }

  float4 fa0, fb0, fa1, fb1, fa2, fb2;
  short8 rw[6];
  float bm0 = -1e30f, bm1 = -1e30f, bm2 = -1e30f;
  int ib0 = 0, ib1 = 0, ib2 = 0;

  // prologue: chunk 0
  c1_ldg(inp, cs, idxs, b, 0, t0, tid, fa0, fb0);
  c1_ldg(inp, cs, idxs, b, 0, t0, tid + 256, fa1, fb1);
  if (tid < 8) c1_ldg(inp, cs, idxs, b, 0, t0, tid + 512, fa2, fb2);
  amax8(bm0, ib0, fa0, fb0, q*8, true);
  amax8(bm1, ib1, fa1, fb1, q*8, true);
  if (tid < 8) amax8(bm2, ib2, fa2, fb2, q*8, true);
  #pragma unroll
  for (int i = 0; i < 6; ++i) rw[i] = c1_ldw(Wp1, 0, tid + i*256);
  c1_wrx(Xs[0], tid, packf(fa0, fb0));
  c1_wrx(Xs[0], tid + 256, packf(fa1, fb1));
  if (tid < 8) c1_wrx(Xs[0], tid + 512, packf(fa2, fb2));
  #pragma unroll
  for (int i = 0; i < 6; ++i) c1_wrw(Ws[0], tid + i*256, rw[i]);
  __syncthreads();

  for (int cc = 0; cc < 5; ++cc) {
    bool more = (cc < 4);
    if (more) {
      c1_ldg(inp, cs, idxs, b, cc+1, t0, tid, fa0, fb0);
      c1_ldg(inp, cs, idxs, b, cc+1, t0, tid + 256, fa1, fb1);
      if (tid < 8) c1_ldg(inp, cs, idxs, b, cc+1, t0, tid + 512, fa2, fb2);
      if (cc < 2) {
        int base = (cc+1)*32 + q*8;
        bool valid = (cc+1 < 2) || (q < 2);
        amax8(bm0, ib0, fa0, fb0, base, valid);
        amax8(bm1, ib1, fa1, fb1, base, valid);
        if (tid < 8) amax8(bm2, ib2, fa2, fb2, base, valid);
      }
      if (cc == 1) {
        #pragma unroll
        for (int d = 1; d <= 2; d <<= 1) {
          float ob; int oi;
          ob = __shfl_xor(bm0, d); oi = __shfl_xor(ib0, d);
          if (ob > bm0 || (ob == bm0 && oi < ib0)) { bm0 = ob; ib0 = oi; }
          ob = __shfl_xor(bm1, d); oi = __shfl_xor(ib1, d);
          if (ob > bm1 || (ob == bm1 && oi < ib1)) { bm1 = ob; ib1 = oi; }
          ob = __shfl_xor(bm2, d); oi = __shfl_xor(ib2, d);
          if (ob > bm2 || (ob == bm2 && oi < ib2)) { bm2 = ob; ib2 = oi; }
        }
        if (q == 0) { idxs[u] = ib0; idxs[u + 64] = ib1; }
        if (tid < 8 && (tid & 3) == 0) idxs[128 + (tid >> 2)] = ib2;
      }
      #pragma unroll
      for (int i = 0; i < 6; ++i) rw[i] = c1_ldw(Wp1, cc+1, tid + i*256);
    }
    int cur = cc & 1;
    #pragma unroll
    for (int k = 0; k < 3; ++k) {
      short8 a0 = *(const short8*)&Xs[cur][wt + ln + k][lq*8];
      short8 a1 = *(const short8*)&Xs[cur][wt + 16 + ln + k][lq*8];
      #pragma unroll
      for (int nt = 0; nt < 8; ++nt) {
        short8 bb = *(const short8*)&Ws[cur][nt*16 + ln][k*32 + lq*8];
        acc[0][nt] = __builtin_amdgcn_mfma_f32_16x16x32_bf16(a0, bb, acc[0][nt], 0, 0, 0);
        acc[1][nt] = __builtin_amdgcn_mfma_f32_16x16x32_bf16(a1, bb, acc[1][nt], 0, 0, 0);
      }
    }
    if (more) {
      int nxt = cur ^ 1;
      c1_wrx(Xs[nxt], tid, packf(fa0, fb0));
      c1_wrx(Xs[nxt], tid + 256, packf(fa1, fb1));
      if (tid < 8) c1_wrx(Xs[nxt], tid + 512, packf(fa2, fb2));
      #pragma unroll
      for (int i = 0; i < 6; ++i) c1_wrw(Ws[nxt], tid + i*256, rw[i]);
    }
    __syncthreads();
  }

  // epilogue: gconst (+edge), fused stats, LDS transpose, contiguous store
  ushort* Ts = &Ws[0][0][0];        // 128 x 136 ushorts, aliases dead Ws
  constexpr int TP = 136;
  #pragma unroll
  for (int nt = 0; nt < 8; ++nt) {
    int o = nt*16 + ln;
    float add = gf[o];
    float s = 0.f, sq = 0.f;
    #pragma unroll
    for (int mt = 0; mt < 2; ++mt) {
      int tl = wt + mt*16 + lq*4;
      #pragma unroll
      for (int r = 0; r < 4; ++r) {
        float v = acc[mt][nt][r] + add;
        int t = t0 + tl + r;
        if (t == 0) v -= g0v[o];
        if (t == T_LEN-1) v -= g2v[o];
        s += v; sq += v*v;
        Ts[(tl + r)*TP + o] = f2b(v);
      }
    }
    s  += __shfl_xor(s, 16);  s  += __shfl_xor(s, 32);
    sq += __shfl_xor(sq, 16); sq += __shfl_xor(sq, 32);
    if (lane < 16) { ps[wave][o] = s; pq[wave][o] = sq; }
  }
  __syncthreads();
  // contiguous 32KB store: y1[b][t0..t0+127][0..127]
  ushort* yb = y1 + ((size_t)b*1024 + t0)*128;
  #pragma unroll
  for (int it = 0; it < 8; ++it) {
    int i = it*256 + tid;
    int tl = i >> 4, c8 = (i & 15) * 8;
    *(uint4*)(yb + tl*128 + c8) = *(const uint4*)(&Ts[tl*TP + c8]);
  }
  if (tid < 128) {
    float S = ps[0][tid]+ps[1][tid]+ps[2][tid]+ps[3][tid];
    float Q = pq[0][tid]+pq[1][tid]+pq[2][tid]+pq[3][tid];
    part1[((size_t)b*128 + tid)*8 + tt] = make_float2(S, Q);
  }
}

// ---- convmid staging helpers (t-major input) ----
__device__ __forceinline__ uint4 mid_ldx(const ushort* __restrict__ xb, int CINv, int cc, int t0, int task) {
  int r = task >> 2, q = task & 3;
  int t = t0 - 1 + r;
  if (t >= 0 && t < T_LEN) return *(const uint4*)(xb + (size_t)t*CINv + cc*32 + q*8);
  return make_uint4(0u,0u,0u,0u);
}
__device__ __forceinline__ void mid_wrx(ushort (*Xsb)[40], const float2* affl, int cbase,
                                        int t0, int task, uint4 v) {
  int r = task >> 2, q = task & 3;
  int t = t0 - 1 + r;
  uint4 w = make_uint4(0u,0u,0u,0u);
  if (t >= 0 && t < T_LEN) {
    const ushort* sv = (const ushort*)&v;
    uint o[4];
    #pragma unroll
    for (int e = 0; e < 4; ++e) {
      float2 A0 = affl[cbase + q*8 + 2*e];
      float2 A1 = affl[cbase + q*8 + 2*e + 1];
      float f0 = fmaxf(0.f, b2f(sv[2*e])*A0.x + A0.y);
      float f1 = fmaxf(0.f, b2f(sv[2*e+1])*A1.x + A1.y);
      o[e] = pack2(f0, f1);
    }
    w = make_uint4(o[0], o[1], o[2], o[3]);
  }
  *(uint4*)&Xsb[r][q*8] = w;
}
__device__ __forceinline__ short8 mid_ldw(const ushort* Wp, int cin, int cc, int task) {
  int o = task / 12, seg = task % 12;
  int k = seg >> 2, oct = seg & 3;
  return *(const short8*)(Wp + ((size_t)o*3 + k)*cin + cc*32 + oct*8);
}
__device__ __forceinline__ void mid_wrw(ushort (*Wsb)[104], int task, short8 v) {
  int o = task / 12, seg = task % 12;
  *(short8*)&Wsb[o][seg*8] = v;
}

// ---- mid convs: t-major in/out, fused GN-stats prologue, 2-phase pipeline, transpose epilogue ----
template<int NC, int CO, int NT, int CPG>
__global__ __launch_bounds__(256) void k_convmid(const ushort* __restrict__ xin,
    const ushort* __restrict__ Wp, const float* __restrict__ bias,
    const float2* __restrict__ partin, const float* __restrict__ gs, const float* __restrict__ gb,
    ushort* __restrict__ yout, float2* __restrict__ part) {
  constexpr int CIN = NC*32;
  constexpr int NG = CIN/CPG;
  constexpr int TP = CO + 8;
  __shared__ __align__(16) ushort Xs[2][130][40];
  __shared__ __align__(16) ushort Ws[2][CO][104];    // aliased as Ts in epilogue
  __shared__ float2 affl[CIN];
  __shared__ float ssb[CIN], qqb[CIN];
  __shared__ float2 gmr[NG];
  __shared__ float bl[CO];
  __shared__ float ps[4][CO], pq[4][CO];
  int b = blockIdx.x, tt = blockIdx.y, t0 = tt*128;
  int tid = threadIdx.x, lane = tid & 63, wave = tid >> 6;
  int ln = lane & 15, lq = lane >> 4, wt = wave*32;
  const ushort* xb = xin + (size_t)b * 1024 * CIN;

  if (tid < CIN) {
    const float2* p = partin + (size_t)(b*CIN + tid)*8;
    float S = 0.f, Q = 0.f;
    #pragma unroll
    for (int j2 = 0; j2 < 8; ++j2) { float2 v = p[j2]; S += v.x; Q += v.y; }
    ssb[tid] = S; qqb[tid] = Q;
  }
  if (tid < CO)  bl[tid]  = bias[tid];

  f32x4 acc[2][NT];
  #pragma unroll
  for (int m = 0; m < 2; ++m)
    #pragma unroll
    for (int n = 0; n < NT; ++n) { f32x4 z = {0.f,0.f,0.f,0.f}; acc[m][n] = z; }

  uint4 rx0, rx1, rx2;
  short8 rw0, rw1, rw2;

  // prologue: raw loads chunk 0
  rx0 = mid_ldx(xb, CIN, 0, t0, tid);
  rx1 = mid_ldx(xb, CIN, 0, t0, tid + 256);
  if (tid < 8) rx2 = mid_ldx(xb, CIN, 0, t0, tid + 512);
  rw0 = mid_ldw(Wp, CIN, 0, tid);
  if constexpr (CO == 64) {
    rw1 = mid_ldw(Wp, CIN, 0, tid + 256);
    rw2 = mid_ldw(Wp, CIN, 0, tid + 512);
  } else {
    if (tid < 128) rw1 = mid_ldw(Wp, CIN, 0, tid + 256);
  }
  __syncthreads();   // ssb/qqb ready
  if (tid < NG) {
    float S = 0.f, Q = 0.f;
    #pragma unroll
    for (int ci = 0; ci < CPG; ++ci) { S += ssb[tid*CPG+ci]; Q += qqb[tid*CPG+ci]; }
    float invn = 1.f / (float)(CPG * T_LEN);
    float m = S * invn;
    float var = Q * invn - m*m;
    gmr[tid] = make_float2(m, rsqrtf(var + 1e-5f));
  }
  __syncthreads();   // gmr ready
  if (tid < CIN) {
    float2 mr = gmr[tid / CPG];
    float a = mr.y * gs[tid];
    affl[tid] = make_float2(a, gb[tid] - mr.x * a);
  }
  __syncthreads();   // affl ready
  mid_wrx(Xs[0], affl, 0, t0, tid, rx0);
  mid_wrx(Xs[0], affl, 0, t0, tid + 256, rx1);
  if (tid < 8) mid_wrx(Xs[0], affl, 0, t0, tid + 512, rx2);
  mid_wrw(Ws[0], tid, rw0);
  if constexpr (CO == 64) {
    mid_wrw(Ws[0], tid + 256, rw1);
    mid_wrw(Ws[0], tid + 512, rw2);
  } else {
    if (tid < 128) mid_wrw(Ws[0], tid + 256, rw1);
  }
  __syncthreads();

  for (int cc = 0; cc < NC; ++cc) {
    bool more = (cc + 1 < NC);
    if (more) {
      rx0 = mid_ldx(xb, CIN, cc+1, t0, tid);
      rx1 = mid_ldx(xb, CIN, cc+1, t0, tid + 256);
      if (tid < 8) rx2 = mid_ldx(xb, CIN, cc+1, t0, tid + 512);
      rw0 = mid_ldw(Wp, CIN, cc+1, tid);
      if constexpr (CO == 64) {
        rw1 = mid_ldw(Wp, CIN, cc+1, tid + 256);
        rw2 = mid_ldw(Wp, CIN, cc+1, tid + 512);
      } else {
        if (tid < 128) rw1 = mid_ldw(Wp, CIN, cc+1, tid + 256);
      }
    }
    int cur = cc & 1;
    #pragma unroll
    for (int k = 0; k < 3; ++k) {
      short8 a0 = *(const short8*)&Xs[cur][wt + ln + k][lq*8];
      short8 a1 = *(const short8*)&Xs[cur][wt + 16 + ln + k][lq*8];
      #pragma unroll
      for (int nt = 0; nt < NT; ++nt) {
        short8 bb = *(const short8*)&Ws[cur][nt*16 + ln][k*32 + lq*8];
        acc[0][nt] = __builtin_amdgcn_mfma_f32_16x16x32_bf16(a0, bb, acc[0][nt], 0, 0, 0);
        acc[1][nt] = __builtin_amdgcn_mfma_f32_16x16x32_bf16(a1, bb, acc[1][nt], 0, 0, 0);
      }
    }
    if (more) {
      int nxt = cur ^ 1;
      mid_wrx(Xs[nxt], affl, (cc+1)*32, t0, tid, rx0);
      mid_wrx(Xs[nxt], affl, (cc+1)*32, t0, tid + 256, rx1);
      if (tid < 8) mid_wrx(Xs[nxt], affl, (cc+1)*32, t0, tid + 512, rx2);
      mid_wrw(Ws[nxt], tid, rw0);
      if constexpr (CO == 64) {
        mid_wrw(Ws[nxt], tid + 256, rw1);
        mid_wrw(Ws[nxt], tid + 512, rw2);
      } else {
        if (tid < 128) mid_wrw(Ws[nxt], tid + 256, rw1);
      }
    }
    __syncthreads();
  }

  // epilogue: bias, fused stats, LDS transpose, contiguous store
  ushort* Ts = &Ws[0][0][0];
  #pragma unroll
  for (int nt = 0; nt < NT; ++nt) {
    int o = nt*16 + ln;
    float add = bl[o];
    float s = 0.f, sq = 0.f;
    #pragma unroll
    for (int mt = 0; mt < 2; ++mt) {
      int tl = wt + mt*16 + lq*4;
      #pragma unroll
      for (int r = 0; r < 4; ++r) {
        float v = acc[mt][nt][r] + add;
        s += v; sq += v*v;
        Ts[(tl + r)*TP + o] = f2b(v);
      }
    }
    s  += __shfl_xor(s, 16);  s  += __shfl_xor(s, 32);
    sq += __shfl_xor(sq, 16); sq += __shfl_xor(sq, 32);
    if (lane < 16) { ps[wave][o] = s; pq[wave][o] = sq; }
  }
  __syncthreads();
  ushort* yb = yout + ((size_t)b*1024 + t0)*CO;
  constexpr int NCH = 128*CO/8;
  #pragma unroll
  for (int it = 0; it < NCH/256; ++it) {
    int i = it*256 + tid;
    int tl = i / (CO/8), c8 = (i % (CO/8)) * 8;
    *(uint4*)(yb + tl*CO + c8) = *(const uint4*)(&Ts[tl*TP + c8]);
  }
  if (tid < CO) {
    float S = ps[0][tid]+ps[1][tid]+ps[2][tid]+ps[3][tid];
    float Q = pq[0][tid]+pq[1][tid]+pq[2][tid]+pq[3][tid];
    part[((size_t)b*CO + tid)*8 + tt] = make_float2(S, Q);
  }
}

// ---- final: y3 is [b][t][32]; contiguous 64B row reads ----
__global__ __launch_bounds__(256) void k_final(const ushort* __restrict__ y3, const float2* __restrict__ part3,
    const float* __restrict__ s3, const float* __restrict__ b3,
    const float* __restrict__ w4, const float* __restrict__ b4,
    const float* __restrict__ mn, const float* __restrict__ sd, float* __restrict__ out) {
  int b = blockIdx.x;
  int t = blockIdx.y * 256 + threadIdx.x;
  __shared__ float wl[32];
  __shared__ float2 al[32];
  if (threadIdx.x < 32) {
    int c = threadIdx.x;
    const float2* p = part3 + (size_t)(b*32 + c)*8;
    float S = 0.f, Q = 0.f;
    #pragma unroll
    for (int j = 0; j < 8; ++j) { float2 v = p[j]; S += v.x; Q += v.y; }
    float invn = 1.f / (float)T_LEN;
    float m = S * invn;
    float var = Q * invn - m*m;
    float rs = rsqrtf(var + 1e-5f);
    float a = rs * s3[c];
    al[c] = make_float2(a, b3[c] - m*a);
    wl[c] = w4[c];
  }
  __syncthreads();
  const ushort* row = y3 + ((size_t)b*1024 + t)*32;
  short8 v0 = *(const short8*)row;
  short8 v1 = *(const short8*)(row + 8);
  short8 v2 = *(const short8*)(row + 16);
  short8 v3 = *(const short8*)(row + 24);
  float s = b4[0];
  #pragma unroll
  for (int e = 0; e < 8; ++e) {
    float2 A0 = al[e], A1 = al[8+e], A2 = al[16+e], A3 = al[24+e];
    s += wl[e]    * fmaxf(0.f, b2f((ushort)v0[e])*A0.x + A0.y);
    s += wl[8+e]  * fmaxf(0.f, b2f((ushort)v1[e])*A1.x + A1.y);
    s += wl[16+e] * fmaxf(0.f, b2f((ushort)v2[e])*A2.x + A2.y);
    s += wl[24+e] * fmaxf(0.f, b2f((ushort)v3[e])*A3.x + A3.y);
  }
  out[(size_t)t*BATCH + b] = s*sd[0] + mn[0];
}

extern "C" void kernel_launch(void* const* d_in, const int* in_sizes, int n_in,
                              void* d_out, int out_size, void* d_ws, size_t ws_size,
                              hipStream_t stream) {
  const float* inp  = (const float*)d_in[0];
  const float* gsty = (const float*)d_in[1];
  const float* cs   = (const float*)d_in[3];
  const float* w1   = (const float*)d_in[4];
  const float* b1   = (const float*)d_in[5];
  const float* gn1s = (const float*)d_in[6];
  const float* gn1b = (const float*)d_in[7];
  const float* w2   = (const float*)d_in[8];
  const float* b2   = (const float*)d_in[9];
  const float* gn2s = (const float*)d_in[10];
  const float* gn2b = (const float*)d_in[11];
  const float* w3   = (const float*)d_in[12];
  const float* b3   = (const float*)d_in[13];
  const float* gn3s = (const float*)d_in[14];
  const float* gn3b = (const float*)d_in[15];
  const float* w4   = (const float*)d_in[16];
  const float* b4   = (const float*)d_in[17];
  const float* mn   = (const float*)d_in[18];
  const float* sd   = (const float*)d_in[19];
  float* out = (float*)d_out;
  ushort* wsu = (ushort*)d_ws;

  ushort* Wp1 = wsu;                               // 61440 sh
  ushort* Wp2 = Wp1 + 61440;                       // 24576 sh
  ushort* Wp3 = Wp2 + 24576;                       // 6144 sh
  float* Gfull = (float*)(Wp3 + 6144);             // 16384 f
  float* Gk0   = Gfull + 16384;
  float* Gk2   = Gk0 + 16384;
  ushort* y1 = (ushort*)(Gk2 + 16384);             // [b][t][128]
  ushort* y2 = y1 + (size_t)NM*128;                // [b][t][64]
  ushort* y3 = y2 + (size_t)NM*64;                 // [b][t][32]
  float2* part1 = (float2*)(y3 + (size_t)NM*32);   // 128*128*8
  float2* part2 = part1 + 131072;                  // 128*64*8
  float2* part3 = part2 + 65536;                   // 128*32*8

  k_prep<<<488, 256, 0, stream>>>(gsty, w1, b1, w2, w3,
                                  Gfull, Gk0, Gk2, Wp1, Wp2, Wp3);
  k_conv1<<<dim3(128,8), 256, 0, stream>>>(inp, cs, Wp1, Gfull, Gk0, Gk2, y1, part1);
  k_convmid<4,64,4,4><<<dim3(128,8), 256, 0, stream>>>(y1, Wp2, b2, part1, gn1s, gn1b, y2, part2);
  k_convmid<2,32,2,2><<<dim3(128,8), 256, 0, stream>>>(y2, Wp3, b3, part2, gn2s, gn2b, y3, part3);
  k_final<<<dim3(128,4), 256, 0, stream>>>(y3, part3, gn3s, gn3b, w4, b4, mn, sd, out);
}